// Round 1
// baseline (111.506 us; speedup 1.0000x reference)
//
#include <hip/hip_runtime.h>

#define NPTS   16384
#define NCHUNK 4
#define CHUNKSZ (NPTS / NCHUNK)   // 4096 B-points staged per block
#define ABLK   256                // A-points per block (= blockDim)
#define NABLK  (NPTS / ABLK)      // 64

// Each block: direction d, A-block ab (256 A-points), B-chunk c (4096 B-points).
// Stages the B-chunk into LDS as {x,y,z, 0.5*|b|^2}, computes per-A-point
// min over the chunk of (0.5*|b|^2 - a.b), writes a^2 + 2*min to partials.
__global__ __launch_bounds__(256) void chamfer_min_kernel(
    const float* __restrict__ adv, const float* __restrict__ ori,
    float* __restrict__ partial /* [NCHUNK][2*NPTS] */) {
  __shared__ float4 bt[CHUNKSZ];  // 64 KB

  const int bx  = blockIdx.x;
  const int c   = bx & (NCHUNK - 1);
  const int t   = bx >> 2;
  const int dir = t & 1;
  const int ab  = t >> 1;

  const float* __restrict__ A = dir ? ori : adv;
  const float* __restrict__ B = dir ? adv : ori;

  const int tid = threadIdx.x;

  // ---- stage B-chunk into LDS (coalesced-ish 12B/thread reads, one-time) ----
  for (int j = tid; j < CHUNKSZ; j += ABLK) {
    const float* bp = B + (size_t)(c * CHUNKSZ + j) * 3;
    const float x = bp[0], y = bp[1], z = bp[2];
    bt[j] = make_float4(x, y, z, 0.5f * (x * x + y * y + z * z));
  }

  // ---- this thread's A point ----
  const int idx = ab * ABLK + tid;
  const float* ap = A + (size_t)idx * 3;
  const float ax = ap[0], ay = ap[1], az = ap[2];
  const float a2 = ax * ax + ay * ay + az * az;

  __syncthreads();

  // ---- min over chunk: 4 independent accumulators to break the min chain ----
  float m0 = 1e30f, m1 = 1e30f, m2 = 1e30f, m3 = 1e30f;
#pragma unroll 4
  for (int j = 0; j < CHUNKSZ; j += 4) {
    const float4 b0 = bt[j + 0];
    const float4 b1 = bt[j + 1];
    const float4 b2 = bt[j + 2];
    const float4 b3 = bt[j + 3];
    const float t0 = b0.w - (ax * b0.x + ay * b0.y + az * b0.z);
    const float t1 = b1.w - (ax * b1.x + ay * b1.y + az * b1.z);
    const float t2 = b2.w - (ax * b2.x + ay * b2.y + az * b2.z);
    const float t3 = b3.w - (ax * b3.x + ay * b3.y + az * b3.z);
    m0 = fminf(m0, t0);
    m1 = fminf(m1, t1);
    m2 = fminf(m2, t2);
    m3 = fminf(m3, t3);
  }
  const float m = fminf(fminf(m0, m1), fminf(m2, m3));

  // d_min over this chunk = |a|^2 + 2 * min(0.5*|b|^2 - a.b)
  partial[c * (2 * NPTS) + dir * NPTS + idx] = a2 + 2.0f * m;
}

// Single block: per-point min over the 4 chunk-partials, sum everything,
// scale by 1/NPTS (mean over each dir; both dirs have the same N so one sum).
__global__ __launch_bounds__(1024) void chamfer_reduce_kernel(
    const float* __restrict__ partial, float* __restrict__ out) {
  __shared__ float red[1024];
  const int tid = threadIdx.x;
  float s = 0.0f;
  for (int j = tid; j < 2 * NPTS; j += 1024) {
    float m = partial[j];
    m = fminf(m, partial[1 * 2 * NPTS + j]);
    m = fminf(m, partial[2 * 2 * NPTS + j]);
    m = fminf(m, partial[3 * 2 * NPTS + j]);
    s += m;
  }
  red[tid] = s;
  __syncthreads();
  for (int off = 512; off > 0; off >>= 1) {
    if (tid < off) red[tid] += red[tid + off];
    __syncthreads();
  }
  if (tid == 0) out[0] = red[0] * (1.0f / (float)NPTS);  // LOSS_WEIGHT = 1
}

extern "C" void kernel_launch(void* const* d_in, const int* in_sizes, int n_in,
                              void* d_out, int out_size, void* d_ws, size_t ws_size,
                              hipStream_t stream) {
  const float* adv = (const float*)d_in[0];
  const float* ori = (const float*)d_in[1];
  float* out = (float*)d_out;
  float* partial = (float*)d_ws;  // needs NCHUNK * 2*NPTS * 4 = 512 KB

  chamfer_min_kernel<<<2 * NABLK * NCHUNK, ABLK, 0, stream>>>(adv, ori, partial);
  chamfer_reduce_kernel<<<1, 1024, 0, stream>>>(partial, out);
}

// Round 2
// 60.202 us; speedup vs baseline: 1.8522x; 1.8522x over previous
//
#include <hip/hip_runtime.h>

#define NPTS    16384
#define NCHUNK  32
#define CHUNKSZ (NPTS / NCHUNK)     // 512 B-points staged per block (8 KB LDS)
#define ABLK    256                 // threads per block
#define ATHREAD 8                   // A-points per thread (amortizes LDS reads)
#define APERBLK (ABLK * ATHREAD)    // 2048 A-points per block
#define NABLK   (NPTS / APERBLK)    // 8 A-blocks per direction

// grid = 2 dirs * NABLK * NCHUNK = 512 blocks.
// Each block: stage CHUNKSZ B-points as {x,y,z,0.5|b|^2} in LDS; each thread
// holds 8 A-points in registers (negated coords -> pure 3-fma chain per pair)
// and min-reduces over the chunk. Cross-chunk combine via deterministic
// atomicMin on uint bit patterns (order-preserving for floats >= 0).
__global__ __launch_bounds__(256) void chamfer_min_kernel(
    const float* __restrict__ adv, const float* __restrict__ ori,
    unsigned int* __restrict__ minbuf /* [2*NPTS] */) {
  __shared__ float4 bt[CHUNKSZ];

  const int bx  = blockIdx.x;
  const int c   = bx & (NCHUNK - 1);
  const int t   = bx >> 5;            // log2(NCHUNK)
  const int dir = t & 1;
  const int ab  = t >> 1;

  const float* __restrict__ A = dir ? ori : adv;
  const float* __restrict__ B = dir ? adv : ori;
  const int tid = threadIdx.x;

  // ---- stage B-chunk into LDS ----
  for (int j = tid; j < CHUNKSZ; j += ABLK) {
    const float* bp = B + (size_t)(c * CHUNKSZ + j) * 3;
    const float x = bp[0], y = bp[1], z = bp[2];
    bt[j] = make_float4(x, y, z, 0.5f * (x * x + y * y + z * z));
  }

  // ---- load this thread's 8 A-points (negated, plus |a|^2) ----
  float nax[ATHREAD], nay[ATHREAD], naz[ATHREAD], a2[ATHREAD], mn[ATHREAD];
#pragma unroll
  for (int k = 0; k < ATHREAD; ++k) {
    const int idx = ab * APERBLK + k * ABLK + tid;
    const float* ap = A + (size_t)idx * 3;
    const float x = ap[0], y = ap[1], z = ap[2];
    nax[k] = -x; nay[k] = -y; naz[k] = -z;
    a2[k] = x * x + y * y + z * z;
    mn[k] = 1e30f;
  }

  __syncthreads();

  // ---- min over chunk: 2 B-points/iter, 8 A-points each ----
  // per pair: 3 fma; per 2 pairs: + 1 min3 => 3.5 VALU/pair
#pragma unroll 4
  for (int j = 0; j < CHUNKSZ; j += 2) {
    const float4 b0 = bt[j];
    const float4 b1 = bt[j + 1];
#pragma unroll
    for (int k = 0; k < ATHREAD; ++k) {
      const float t0 = fmaf(nax[k], b0.x, fmaf(nay[k], b0.y, fmaf(naz[k], b0.z, b0.w)));
      const float t1 = fmaf(nax[k], b1.x, fmaf(nay[k], b1.y, fmaf(naz[k], b1.z, b1.w)));
      mn[k] = fminf(fminf(mn[k], t0), t1);  // -> v_min3_f32
    }
  }

  // ---- d_min(chunk) = |a|^2 + 2*min(0.5|b|^2 - a.b); combine via atomicMin ----
#pragma unroll
  for (int k = 0; k < ATHREAD; ++k) {
    const int idx = ab * APERBLK + k * ABLK + tid;
    const float v = fmaf(2.0f, mn[k], a2[k]);
    atomicMin(&minbuf[dir * NPTS + idx], __float_as_uint(v));
  }
}

// Single block: sum all 2*NPTS per-point mins, scale by 1/NPTS.
__global__ __launch_bounds__(1024) void chamfer_reduce_kernel(
    const unsigned int* __restrict__ minbuf, float* __restrict__ out) {
  __shared__ float red[1024];
  const int tid = threadIdx.x;
  float s = 0.0f;
  for (int j = tid; j < 2 * NPTS; j += 1024) {
    s += __uint_as_float(minbuf[j]);
  }
  red[tid] = s;
  __syncthreads();
  for (int off = 512; off > 0; off >>= 1) {
    if (tid < off) red[tid] += red[tid + off];
    __syncthreads();
  }
  if (tid == 0) out[0] = red[0] * (1.0f / (float)NPTS);  // LOSS_WEIGHT = 1
}

extern "C" void kernel_launch(void* const* d_in, const int* in_sizes, int n_in,
                              void* d_out, int out_size, void* d_ws, size_t ws_size,
                              hipStream_t stream) {
  const float* adv = (const float*)d_in[0];
  const float* ori = (const float*)d_in[1];
  float* out = (float*)d_out;
  unsigned int* minbuf = (unsigned int*)d_ws;  // 2*NPTS*4 = 128 KB

  // init mins to +huge (0x7F7F7F7F as uint > any finite non-negative float pattern)
  hipMemsetAsync(minbuf, 0x7F, (size_t)(2 * NPTS) * sizeof(unsigned int), stream);

  chamfer_min_kernel<<<2 * NABLK * NCHUNK, ABLK, 0, stream>>>(adv, ori, minbuf);
  chamfer_reduce_kernel<<<1, 1024, 0, stream>>>(minbuf, out);
}

// Round 3
// 37.101 us; speedup vs baseline: 3.0055x; 1.6227x over previous
//
#include <hip/hip_runtime.h>

#define NPTS 16384

typedef short bf16x8 __attribute__((ext_vector_type(8)));
typedef float f32x16 __attribute__((ext_vector_type(16)));
typedef unsigned short us8v __attribute__((ext_vector_type(8)));

__device__ __forceinline__ unsigned short f2bf(float x) {
  unsigned int u = __float_as_uint(x);
  u = (u + 0x7FFFu + ((u >> 16) & 1u)) >> 16;   // RNE
  return (unsigned short)u;
}
__device__ __forceinline__ float bf2f(unsigned short h) {
  return __uint_as_float(((unsigned int)h) << 16);
}

// ---------------------------------------------------------------------------
// Prepack: for each point p of each set, build the MFMA-A-operand features
// F_p[16] (bf16): per coord c: {hi(-2p_c), hi, lo(-2p_c), lo}; ch12-14 =
// 3-way split of |p|^2; ch15 = 0.  S[p][q] = F_p . G_q = |p|^2 - 2 p.q, so
// d = S + |q|^2.  Stored tile-interleaved: tile t=p>>5 is 1024 B; point j=p&31
// half h at byte t*1024 + h*512 + j*16 — exactly the 32x32x16 A-frag order
// (lane l <- point l&31, k-half l>>5), so staging and ds_read are linear.
// ---------------------------------------------------------------------------
__global__ __launch_bounds__(256) void prepack_kernel(
    const float* __restrict__ adv, const float* __restrict__ ori,
    unsigned short* __restrict__ Fall) {
  const int id = blockIdx.x * 256 + threadIdx.x;  // 0..32767
  const int s = id >> 14;
  const int p = id & (NPTS - 1);
  const float* P = s ? ori : adv;
  const float x = P[p * 3 + 0], y = P[p * 3 + 1], z = P[p * 3 + 2];

  unsigned short o[16];
  const float co[3] = {x, y, z};
#pragma unroll
  for (int c = 0; c < 3; ++c) {
    const float t = -2.0f * co[c];
    const unsigned short hi = f2bf(t);
    const unsigned short lo = f2bf(t - bf2f(hi));
    o[4 * c + 0] = hi; o[4 * c + 1] = hi;
    o[4 * c + 2] = lo; o[4 * c + 3] = lo;
  }
  const float w = x * x + y * y + z * z;
  const unsigned short whi = f2bf(w);
  const float w1 = w - bf2f(whi);
  const unsigned short wmid = f2bf(w1);
  const unsigned short wlo = f2bf(w1 - bf2f(wmid));
  o[12] = whi; o[13] = wmid; o[14] = wlo; o[15] = 0;

  unsigned short* base = Fall + (size_t)s * (NPTS * 16) + (p >> 5) * 512 + (p & 31) * 8;
  us8v h0, h1;
#pragma unroll
  for (int i = 0; i < 8; ++i) { h0[i] = o[i]; h1[i] = o[8 + i]; }
  *(us8v*)(base) = h0;          // half 0 (ch 0-7)
  *(us8v*)(base + 256) = h1;    // half 1 (ch 8-15)
}

// ---------------------------------------------------------------------------
// Main: 256 blocks x 512 thr (8 waves). bid -> {dir, A-group(512 pts), B-chunk
// (4096 pts)}. Each wave: 2 A-tiles (G-frags built in-register: lane l = col
// l&31, k-half l>>5), loops 128 B-tiles: 1 ds_read_b128 + 2 mfma_32x32x16_bf16
// + 16 v_min3. B staged via global_load_lds, double-buffered 2x32KB.
// ---------------------------------------------------------------------------
__global__ __launch_bounds__(512, 2) void chamfer_mfma_kernel(
    const float* __restrict__ adv, const float* __restrict__ ori,
    const unsigned short* __restrict__ Fall,
    unsigned int* __restrict__ minbuf) {
  __shared__ short lds[2][16384];  // 2 x 32 KB

  const int bid = blockIdx.x;
  const int dir = bid >> 7;
  const int rr = bid & 127;
  const int ag = rr >> 2;  // 0..31  A-group
  const int cc = rr & 3;   // 0..3   B-chunk

  const float* __restrict__ A = dir ? ori : adv;
  const unsigned short* __restrict__ F = Fall + (size_t)(1 - dir) * (NPTS * 16);

  const int w = threadIdx.x >> 6;
  const int lane = threadIdx.x & 63;
  const int col = lane & 31;
  const int half = lane >> 5;

  // ---- G fragments (MFMA B-operand) for this wave's 2 A-tiles ----
  const int at0 = ag * 16 + w * 2;
  const int q0 = at0 * 32 + col;
  const int q1 = q0 + 32;
  const float x0 = A[q0 * 3], y0 = A[q0 * 3 + 1], z0 = A[q0 * 3 + 2];
  const float x1 = A[q1 * 3], y1 = A[q1 * 3 + 1], z1 = A[q1 * 3 + 2];

  const unsigned short ONE = 0x3F80;
  bf16x8 g0, g1;
  {
    unsigned short xh = f2bf(x0), xl = f2bf(x0 - bf2f(xh));
    unsigned short yh = f2bf(y0), yl = f2bf(y0 - bf2f(yh));
    unsigned short zh = f2bf(z0), zl = f2bf(z0 - bf2f(zh));
    g0[0] = half ? zh : xh; g0[1] = half ? zl : xl;
    g0[2] = half ? zh : xh; g0[3] = half ? zl : xl;
    g0[4] = half ? ONE : yh; g0[5] = half ? ONE : yl;
    g0[6] = half ? ONE : yh; g0[7] = half ? (unsigned short)0 : yl;
  }
  {
    unsigned short xh = f2bf(x1), xl = f2bf(x1 - bf2f(xh));
    unsigned short yh = f2bf(y1), yl = f2bf(y1 - bf2f(yh));
    unsigned short zh = f2bf(z1), zl = f2bf(z1 - bf2f(zh));
    g1[0] = half ? zh : xh; g1[1] = half ? zl : xl;
    g1[2] = half ? zh : xh; g1[3] = half ? zl : xl;
    g1[4] = half ? ONE : yh; g1[5] = half ? ONE : yl;
    g1[6] = half ? ONE : yh; g1[7] = half ? (unsigned short)0 : yl;
  }

  const unsigned short* Fc = F + cc * (4096 * 16);  // chunk base

  // stage round r (1024 pts = 32 KB) into lds[buf]; 4 x 1KB segments per wave
  auto stage = [&](int r, int buf) {
    const char* src = (const char*)(Fc + r * 16384);
#pragma unroll
    for (int s = 0; s < 4; ++s) {
      const int seg = w * 4 + s;
      __builtin_amdgcn_global_load_lds(
          (const __attribute__((address_space(1))) void*)(src + seg * 1024 + lane * 16),
          (__attribute__((address_space(3))) void*)((char*)&lds[buf][0] + seg * 1024),
          16, 0, 0);
    }
  };

  f32x16 zacc = {};  // zero C operand, kept in regs
  float m0a = 1e30f, m0b = 1e30f, m1a = 1e30f, m1b = 1e30f;

  stage(0, 0);
  for (int r = 0; r < 4; ++r) {
    __syncthreads();  // compiler emits vmcnt(0) drain before barrier -> buf ready
    if (r < 3) stage(r + 1, (r + 1) & 1);
    const short* Lb = &lds[r & 1][0];

    bf16x8 f = *(const bf16x8*)(Lb + lane * 8);  // tile 0 prefetch
#pragma unroll 2
    for (int tt = 0; tt < 32; ++tt) {
      const int nt = (tt + 1) & 31;
      const bf16x8 fn = *(const bf16x8*)(Lb + nt * 512 + lane * 8);  // next-tile prefetch
      const f32x16 a0 = __builtin_amdgcn_mfma_f32_32x32x16_bf16(f, g0, zacc, 0, 0, 0);
      const f32x16 a1 = __builtin_amdgcn_mfma_f32_32x32x16_bf16(f, g1, zacc, 0, 0, 0);
      m0a = fminf(fminf(m0a, a0[0]), a0[1]);
      m0a = fminf(fminf(m0a, a0[2]), a0[3]);
      m0a = fminf(fminf(m0a, a0[4]), a0[5]);
      m0a = fminf(fminf(m0a, a0[6]), a0[7]);
      m0b = fminf(fminf(m0b, a0[8]), a0[9]);
      m0b = fminf(fminf(m0b, a0[10]), a0[11]);
      m0b = fminf(fminf(m0b, a0[12]), a0[13]);
      m0b = fminf(fminf(m0b, a0[14]), a0[15]);
      m1a = fminf(fminf(m1a, a1[0]), a1[1]);
      m1a = fminf(fminf(m1a, a1[2]), a1[3]);
      m1a = fminf(fminf(m1a, a1[4]), a1[5]);
      m1a = fminf(fminf(m1a, a1[6]), a1[7]);
      m1b = fminf(fminf(m1b, a1[8]), a1[9]);
      m1b = fminf(fminf(m1b, a1[10]), a1[11]);
      m1b = fminf(fminf(m1b, a1[12]), a1[13]);
      m1b = fminf(fminf(m1b, a1[14]), a1[15]);
      f = fn;
    }
  }

  // ---- epilogue: fold halves (rows 16-31 live in lanes^32), add |q|^2 ----
  float mc0 = fminf(m0a, m0b);
  float mc1 = fminf(m1a, m1b);
  mc0 = fminf(mc0, __shfl_xor(mc0, 32));
  mc1 = fminf(mc1, __shfl_xor(mc1, 32));
  const float d0 = fmaxf(mc0 + (x0 * x0 + y0 * y0 + z0 * z0), 0.0f);
  const float d1 = fmaxf(mc1 + (x1 * x1 + y1 * y1 + z1 * z1), 0.0f);
  if (half == 0) {
    atomicMin(&minbuf[dir * NPTS + q0], __float_as_uint(d0));
    atomicMin(&minbuf[dir * NPTS + q1], __float_as_uint(d1));
  }
}

// ---------------------------------------------------------------------------
// Fallback (ws too small): round-2 VALU kernel.
// ---------------------------------------------------------------------------
__global__ __launch_bounds__(256) void chamfer_valu_kernel(
    const float* __restrict__ adv, const float* __restrict__ ori,
    unsigned int* __restrict__ minbuf) {
  __shared__ float4 bt[512];
  const int bx = blockIdx.x;
  const int c = bx & 31;
  const int t = bx >> 5;
  const int dir = t & 1;
  const int ab = t >> 1;
  const float* __restrict__ A = dir ? ori : adv;
  const float* __restrict__ B = dir ? adv : ori;
  const int tid = threadIdx.x;
  for (int j = tid; j < 512; j += 256) {
    const float* bp = B + (size_t)(c * 512 + j) * 3;
    const float x = bp[0], y = bp[1], z = bp[2];
    bt[j] = make_float4(x, y, z, 0.5f * (x * x + y * y + z * z));
  }
  float nax[8], nay[8], naz[8], a2[8], mn[8];
#pragma unroll
  for (int k = 0; k < 8; ++k) {
    const int idx = ab * 2048 + k * 256 + tid;
    const float* ap = A + (size_t)idx * 3;
    const float x = ap[0], y = ap[1], z = ap[2];
    nax[k] = -x; nay[k] = -y; naz[k] = -z;
    a2[k] = x * x + y * y + z * z;
    mn[k] = 1e30f;
  }
  __syncthreads();
#pragma unroll 4
  for (int j = 0; j < 512; j += 2) {
    const float4 b0 = bt[j];
    const float4 b1 = bt[j + 1];
#pragma unroll
    for (int k = 0; k < 8; ++k) {
      const float t0 = fmaf(nax[k], b0.x, fmaf(nay[k], b0.y, fmaf(naz[k], b0.z, b0.w)));
      const float t1 = fmaf(nax[k], b1.x, fmaf(nay[k], b1.y, fmaf(naz[k], b1.z, b1.w)));
      mn[k] = fminf(fminf(mn[k], t0), t1);
    }
  }
#pragma unroll
  for (int k = 0; k < 8; ++k) {
    const int idx = ab * 2048 + k * 256 + tid;
    const float v = fmaf(2.0f, mn[k], a2[k]);
    atomicMin(&minbuf[dir * NPTS + idx], __float_as_uint(v));
  }
}

__global__ __launch_bounds__(1024) void chamfer_reduce_kernel(
    const unsigned int* __restrict__ minbuf, float* __restrict__ out) {
  __shared__ float red[1024];
  const int tid = threadIdx.x;
  float s = 0.0f;
  for (int j = tid; j < 2 * NPTS; j += 1024) s += __uint_as_float(minbuf[j]);
  red[tid] = s;
  __syncthreads();
  for (int off = 512; off > 0; off >>= 1) {
    if (tid < off) red[tid] += red[tid + off];
    __syncthreads();
  }
  if (tid == 0) out[0] = red[0] * (1.0f / (float)NPTS);
}

extern "C" void kernel_launch(void* const* d_in, const int* in_sizes, int n_in,
                              void* d_out, int out_size, void* d_ws, size_t ws_size,
                              hipStream_t stream) {
  const float* adv = (const float*)d_in[0];
  const float* ori = (const float*)d_in[1];
  float* out = (float*)d_out;
  unsigned int* minbuf = (unsigned int*)d_ws;

  const size_t need = 131072 + (size_t)2 * NPTS * 16 * sizeof(unsigned short);  // 128K + 1M
  hipMemsetAsync(minbuf, 0x7F, (size_t)(2 * NPTS) * sizeof(unsigned int), stream);

  if (ws_size >= need) {
    unsigned short* Fall = (unsigned short*)((char*)d_ws + 131072);
    prepack_kernel<<<128, 256, 0, stream>>>(adv, ori, Fall);
    chamfer_mfma_kernel<<<256, 512, 0, stream>>>(adv, ori, Fall, minbuf);
  } else {
    chamfer_valu_kernel<<<1024, 256, 0, stream>>>(adv, ori, minbuf);
  }
  chamfer_reduce_kernel<<<1, 1024, 0, stream>>>(minbuf, out);
}

// Round 4
// 28.633 us; speedup vs baseline: 3.8943x; 1.2957x over previous
//
#include <hip/hip_runtime.h>

#define NPTS 16384

typedef short bf16x8 __attribute__((ext_vector_type(8)));
typedef float f32x16 __attribute__((ext_vector_type(16)));
typedef unsigned short us8v __attribute__((ext_vector_type(8)));

__device__ __forceinline__ unsigned short f2bf(float x) {
  unsigned int u = __float_as_uint(x);
  u = (u + 0x7FFFu + ((u >> 16) & 1u)) >> 16;   // RNE
  return (unsigned short)u;
}
__device__ __forceinline__ float bf2f(unsigned short h) {
  return __uint_as_float(((unsigned int)h) << 16);
}

// ---------------------------------------------------------------------------
// Prepack: per point p, MFMA-A-operand features F_p[16] (bf16): per coord c:
// {hi(-2p_c), hi, lo(-2p_c), lo}; ch12-14 = 3-way split of |p|^2; ch15 = 0.
// S[p][q] = F_p . G_q = |p|^2 - 2 p.q, so d = S + |q|^2.  Tile-interleaved
// layout = exact 32x32x16 A-frag order (lane l <- point l&31, k-half l>>5),
// so global_load_lds staging and ds_read_b128 are both linear.
// ALSO initializes minbuf (one element per thread) — replaces the slow
// rocclr fillBuffer dispatch seen in round-3 profiling.
// ---------------------------------------------------------------------------
__global__ __launch_bounds__(256) void prepack_kernel(
    const float* __restrict__ adv, const float* __restrict__ ori,
    unsigned short* __restrict__ Fall, unsigned int* __restrict__ minbuf) {
  const int id = blockIdx.x * 256 + threadIdx.x;  // 0..32767
  minbuf[id] = 0x7F7F7F7Fu;  // > any finite non-negative float bit pattern

  const int s = id >> 14;
  const int p = id & (NPTS - 1);
  const float* P = s ? ori : adv;
  const float x = P[p * 3 + 0], y = P[p * 3 + 1], z = P[p * 3 + 2];

  unsigned short o[16];
  const float co[3] = {x, y, z};
#pragma unroll
  for (int c = 0; c < 3; ++c) {
    const float t = -2.0f * co[c];
    const unsigned short hi = f2bf(t);
    const unsigned short lo = f2bf(t - bf2f(hi));
    o[4 * c + 0] = hi; o[4 * c + 1] = hi;
    o[4 * c + 2] = lo; o[4 * c + 3] = lo;
  }
  const float w = x * x + y * y + z * z;
  const unsigned short whi = f2bf(w);
  const float w1 = w - bf2f(whi);
  const unsigned short wmid = f2bf(w1);
  const unsigned short wlo = f2bf(w1 - bf2f(wmid));
  o[12] = whi; o[13] = wmid; o[14] = wlo; o[15] = 0;

  unsigned short* base = Fall + (size_t)s * (NPTS * 16) + (p >> 5) * 512 + (p & 31) * 8;
  us8v h0, h1;
#pragma unroll
  for (int i = 0; i < 8; ++i) { h0[i] = o[i]; h1[i] = o[8 + i]; }
  *(us8v*)(base) = h0;          // half 0 (ch 0-7)
  *(us8v*)(base + 256) = h1;    // half 1 (ch 8-15)
}

// ---------------------------------------------------------------------------
// Main: 256 blocks x 512 thr (8 waves). bid -> {dir, A-group(512 pts), B-chunk
// (4096 pts)}. Each wave: 2 A-tiles (G-frags in-register), loops 128 B-tiles:
// 1 ds_read_b128 + 2 mfma_32x32x16_bf16 + 16 v_min3. B staged via
// global_load_lds, double-buffered 2x32KB.
// ---------------------------------------------------------------------------
__global__ __launch_bounds__(512, 2) void chamfer_mfma_kernel(
    const float* __restrict__ adv, const float* __restrict__ ori,
    const unsigned short* __restrict__ Fall,
    unsigned int* __restrict__ minbuf) {
  __shared__ short lds[2][16384];  // 2 x 32 KB

  const int bid = blockIdx.x;
  const int dir = bid >> 7;
  const int rr = bid & 127;
  const int ag = rr >> 2;  // 0..31  A-group
  const int cc = rr & 3;   // 0..3   B-chunk

  const float* __restrict__ A = dir ? ori : adv;
  const unsigned short* __restrict__ F = Fall + (size_t)(1 - dir) * (NPTS * 16);

  const int w = threadIdx.x >> 6;
  const int lane = threadIdx.x & 63;
  const int col = lane & 31;
  const int half = lane >> 5;

  // ---- G fragments (MFMA B-operand) for this wave's 2 A-tiles ----
  const int at0 = ag * 16 + w * 2;
  const int q0 = at0 * 32 + col;
  const int q1 = q0 + 32;
  const float x0 = A[q0 * 3], y0 = A[q0 * 3 + 1], z0 = A[q0 * 3 + 2];
  const float x1 = A[q1 * 3], y1 = A[q1 * 3 + 1], z1 = A[q1 * 3 + 2];

  const unsigned short ONE = 0x3F80;
  bf16x8 g0, g1;
  {
    unsigned short xh = f2bf(x0), xl = f2bf(x0 - bf2f(xh));
    unsigned short yh = f2bf(y0), yl = f2bf(y0 - bf2f(yh));
    unsigned short zh = f2bf(z0), zl = f2bf(z0 - bf2f(zh));
    g0[0] = half ? zh : xh; g0[1] = half ? zl : xl;
    g0[2] = half ? zh : xh; g0[3] = half ? zl : xl;
    g0[4] = half ? ONE : yh; g0[5] = half ? ONE : yl;
    g0[6] = half ? ONE : yh; g0[7] = half ? (unsigned short)0 : yl;
  }
  {
    unsigned short xh = f2bf(x1), xl = f2bf(x1 - bf2f(xh));
    unsigned short yh = f2bf(y1), yl = f2bf(y1 - bf2f(yh));
    unsigned short zh = f2bf(z1), zl = f2bf(z1 - bf2f(zh));
    g1[0] = half ? zh : xh; g1[1] = half ? zl : xl;
    g1[2] = half ? zh : xh; g1[3] = half ? zl : xl;
    g1[4] = half ? ONE : yh; g1[5] = half ? ONE : yl;
    g1[6] = half ? ONE : yh; g1[7] = half ? (unsigned short)0 : yl;
  }

  const unsigned short* Fc = F + cc * (4096 * 16);  // chunk base

  auto stage = [&](int r, int buf) {
    const char* src = (const char*)(Fc + r * 16384);
#pragma unroll
    for (int s = 0; s < 4; ++s) {
      const int seg = w * 4 + s;
      __builtin_amdgcn_global_load_lds(
          (const __attribute__((address_space(1))) void*)(src + seg * 1024 + lane * 16),
          (__attribute__((address_space(3))) void*)((char*)&lds[buf][0] + seg * 1024),
          16, 0, 0);
    }
  };

  f32x16 zacc = {};
  float m0a = 1e30f, m0b = 1e30f, m1a = 1e30f, m1b = 1e30f;

  stage(0, 0);
  for (int r = 0; r < 4; ++r) {
    __syncthreads();  // vmcnt(0) drain before barrier -> buf ready
    if (r < 3) stage(r + 1, (r + 1) & 1);
    const short* Lb = &lds[r & 1][0];

    bf16x8 f = *(const bf16x8*)(Lb + lane * 8);  // tile 0 prefetch
#pragma unroll 2
    for (int tt = 0; tt < 32; ++tt) {
      const int nt = (tt + 1) & 31;
      const bf16x8 fn = *(const bf16x8*)(Lb + nt * 512 + lane * 8);
      const f32x16 a0 = __builtin_amdgcn_mfma_f32_32x32x16_bf16(f, g0, zacc, 0, 0, 0);
      const f32x16 a1 = __builtin_amdgcn_mfma_f32_32x32x16_bf16(f, g1, zacc, 0, 0, 0);
      m0a = fminf(fminf(m0a, a0[0]), a0[1]);
      m0a = fminf(fminf(m0a, a0[2]), a0[3]);
      m0a = fminf(fminf(m0a, a0[4]), a0[5]);
      m0a = fminf(fminf(m0a, a0[6]), a0[7]);
      m0b = fminf(fminf(m0b, a0[8]), a0[9]);
      m0b = fminf(fminf(m0b, a0[10]), a0[11]);
      m0b = fminf(fminf(m0b, a0[12]), a0[13]);
      m0b = fminf(fminf(m0b, a0[14]), a0[15]);
      m1a = fminf(fminf(m1a, a1[0]), a1[1]);
      m1a = fminf(fminf(m1a, a1[2]), a1[3]);
      m1a = fminf(fminf(m1a, a1[4]), a1[5]);
      m1a = fminf(fminf(m1a, a1[6]), a1[7]);
      m1b = fminf(fminf(m1b, a1[8]), a1[9]);
      m1b = fminf(fminf(m1b, a1[10]), a1[11]);
      m1b = fminf(fminf(m1b, a1[12]), a1[13]);
      m1b = fminf(fminf(m1b, a1[14]), a1[15]);
      f = fn;
    }
  }

  float mc0 = fminf(m0a, m0b);
  float mc1 = fminf(m1a, m1b);
  mc0 = fminf(mc0, __shfl_xor(mc0, 32));
  mc1 = fminf(mc1, __shfl_xor(mc1, 32));
  const float d0 = fmaxf(mc0 + (x0 * x0 + y0 * y0 + z0 * z0), 0.0f);
  const float d1 = fmaxf(mc1 + (x1 * x1 + y1 * y1 + z1 * z1), 0.0f);
  if (half == 0) {
    atomicMin(&minbuf[dir * NPTS + q0], __float_as_uint(d0));
    atomicMin(&minbuf[dir * NPTS + q1], __float_as_uint(d1));
  }
}

// ---------------------------------------------------------------------------
// Fallback (ws too small): round-2 VALU kernel.
// ---------------------------------------------------------------------------
__global__ __launch_bounds__(256) void chamfer_valu_kernel(
    const float* __restrict__ adv, const float* __restrict__ ori,
    unsigned int* __restrict__ minbuf) {
  __shared__ float4 bt[512];
  const int bx = blockIdx.x;
  const int c = bx & 31;
  const int t = bx >> 5;
  const int dir = t & 1;
  const int ab = t >> 1;
  const float* __restrict__ A = dir ? ori : adv;
  const float* __restrict__ B = dir ? adv : ori;
  const int tid = threadIdx.x;
  for (int j = tid; j < 512; j += 256) {
    const float* bp = B + (size_t)(c * 512 + j) * 3;
    const float x = bp[0], y = bp[1], z = bp[2];
    bt[j] = make_float4(x, y, z, 0.5f * (x * x + y * y + z * z));
  }
  float nax[8], nay[8], naz[8], a2[8], mn[8];
#pragma unroll
  for (int k = 0; k < 8; ++k) {
    const int idx = ab * 2048 + k * 256 + tid;
    const float* ap = A + (size_t)idx * 3;
    const float x = ap[0], y = ap[1], z = ap[2];
    nax[k] = -x; nay[k] = -y; naz[k] = -z;
    a2[k] = x * x + y * y + z * z;
    mn[k] = 1e30f;
  }
  __syncthreads();
#pragma unroll 4
  for (int j = 0; j < 512; j += 2) {
    const float4 b0 = bt[j];
    const float4 b1 = bt[j + 1];
#pragma unroll
    for (int k = 0; k < 8; ++k) {
      const float t0 = fmaf(nax[k], b0.x, fmaf(nay[k], b0.y, fmaf(naz[k], b0.z, b0.w)));
      const float t1 = fmaf(nax[k], b1.x, fmaf(nay[k], b1.y, fmaf(naz[k], b1.z, b1.w)));
      mn[k] = fminf(fminf(mn[k], t0), t1);
    }
  }
#pragma unroll
  for (int k = 0; k < 8; ++k) {
    const int idx = ab * 2048 + k * 256 + tid;
    const float v = fmaf(2.0f, mn[k], a2[k]);
    atomicMin(&minbuf[dir * NPTS + idx], __float_as_uint(v));
  }
}

// Single block: sum all 2*NPTS per-point mins (uint4-vectorized), /NPTS.
__global__ __launch_bounds__(1024) void chamfer_reduce_kernel(
    const unsigned int* __restrict__ minbuf, float* __restrict__ out) {
  __shared__ float red[1024];
  const int tid = threadIdx.x;
  const uint4* mb4 = (const uint4*)minbuf;
  float s = 0.0f;
#pragma unroll
  for (int it = 0; it < 8; ++it) {
    const uint4 v = mb4[it * 1024 + tid];
    s += __uint_as_float(v.x) + __uint_as_float(v.y) +
         __uint_as_float(v.z) + __uint_as_float(v.w);
  }
  red[tid] = s;
  __syncthreads();
  for (int off = 512; off > 0; off >>= 1) {
    if (tid < off) red[tid] += red[tid + off];
    __syncthreads();
  }
  if (tid == 0) out[0] = red[0] * (1.0f / (float)NPTS);  // LOSS_WEIGHT = 1
}

extern "C" void kernel_launch(void* const* d_in, const int* in_sizes, int n_in,
                              void* d_out, int out_size, void* d_ws, size_t ws_size,
                              hipStream_t stream) {
  const float* adv = (const float*)d_in[0];
  const float* ori = (const float*)d_in[1];
  float* out = (float*)d_out;
  unsigned int* minbuf = (unsigned int*)d_ws;

  const size_t need = 131072 + (size_t)2 * NPTS * 16 * sizeof(unsigned short);  // 128K + 1M

  if (ws_size >= need) {
    unsigned short* Fall = (unsigned short*)((char*)d_ws + 131072);
    prepack_kernel<<<128, 256, 0, stream>>>(adv, ori, Fall, minbuf);  // also inits minbuf
    chamfer_mfma_kernel<<<256, 512, 0, stream>>>(adv, ori, Fall, minbuf);
  } else {
    hipMemsetAsync(minbuf, 0x7F, (size_t)(2 * NPTS) * sizeof(unsigned int), stream);
    chamfer_valu_kernel<<<1024, 256, 0, stream>>>(adv, ori, minbuf);
  }
  chamfer_reduce_kernel<<<1, 1024, 0, stream>>>(minbuf, out);
}